// Round 1
// baseline (114.255 us; speedup 1.0000x reference)
//
#include <hip/hip_runtime.h>

#define VOCAB 100000
#define D     300
#define B     256
#define L     1000
#define H     512
#define C     5

#define SPLIT 10
#define CHUNK (L / SPLIT)   // 100 rows per block
#define D4    (D / 4)       // 75 float4 per row
#define BB    2             // batch rows per MLP block

// ---------------------------------------------------------------------------
// Kernel 1: gather + partial sum.
// grid = (B, SPLIT), block = 320 threads = 4 row-groups x 80 lanes.
// Each row-group loads one embedding row per iteration as float4 (16B/lane).
// Partial sums for each (b, split) chunk go to d_ws: partial[B*SPLIT][D].
// ---------------------------------------------------------------------------
__global__ __launch_bounds__(320) void gather_sum_kernel(
    const float* __restrict__ emb, const int* __restrict__ docs,
    float* __restrict__ partial) {
  const int b = blockIdx.x;
  const int s = blockIdx.y;
  const int t = threadIdx.x;
  const int rg = t / 80;        // row group 0..3
  const int lane = t - rg * 80; // 0..79, active < 75

  __shared__ int sidx[CHUNK];
  if (t < CHUNK) sidx[t] = docs[b * L + s * CHUNK + t];
  __syncthreads();

  float ax = 0.f, ay = 0.f, az = 0.f, aw = 0.f;
  if (lane < D4) {
#pragma unroll 5
    for (int l = 0; l < CHUNK; l += 4) {
      const int idx = sidx[l + rg];
      const float4* row =
          reinterpret_cast<const float4*>(emb + (size_t)idx * D);
      const float4 v = row[lane];
      ax += v.x; ay += v.y; az += v.z; aw += v.w;
    }
  }

  __shared__ float4 sred[3][D4];
  if (rg > 0 && lane < D4) {
    sred[rg - 1][lane] = make_float4(ax, ay, az, aw);
  }
  __syncthreads();
  if (rg == 0 && lane < D4) {
#pragma unroll
    for (int g = 0; g < 3; ++g) {
      const float4 v = sred[g][lane];
      ax += v.x; ay += v.y; az += v.z; aw += v.w;
    }
    float4* dst =
        reinterpret_cast<float4*>(partial + (size_t)(b * SPLIT + s) * D);
    dst[lane] = make_float4(ax, ay, az, aw);
  }
}

// ---------------------------------------------------------------------------
// Kernel 2: reduce partials -> avg, then MLP 300 -> 512 -> 512 -> 5.
// grid = B/BB = 128 blocks, block = 512 threads (one per hidden unit).
// ---------------------------------------------------------------------------
__global__ __launch_bounds__(512) void mlp_kernel(
    const float* __restrict__ partial, const int* __restrict__ dlen,
    const float* __restrict__ W1, const float* __restrict__ b1,
    const float* __restrict__ W2, const float* __restrict__ b2,
    const float* __restrict__ W3, const float* __restrict__ b3,
    float* __restrict__ out) {
  const int r0 = blockIdx.x * BB;
  const int t = threadIdx.x;

  __shared__ float s_avg[BB][D];
  __shared__ float s_h1[BB][H];
  __shared__ float s_h2[BB][H];

  // Stage averaged inputs into LDS.
  for (int i = t; i < BB * D; i += 512) {
    const int bb = i / D;
    const int d = i - bb * D;
    const int b = r0 + bb;
    const float* p = partial + (size_t)b * SPLIT * D + d;
    float sum = 0.f;
#pragma unroll
    for (int s = 0; s < SPLIT; ++s) sum += p[s * D];
    s_avg[bb][d] = sum / (float)dlen[b];
  }
  __syncthreads();

  // Layer 1: h1 = relu(avg @ W1 + b1). Thread t owns hidden unit t.
  {
    const float bias = b1[t];
    float acc0 = bias, acc1 = bias;
#pragma unroll 4
    for (int d = 0; d < D; ++d) {
      const float w = W1[d * H + t];
      acc0 += s_avg[0][d] * w;
      acc1 += s_avg[1][d] * w;
    }
    s_h1[0][t] = fmaxf(acc0, 0.f);
    s_h1[1][t] = fmaxf(acc1, 0.f);
  }
  __syncthreads();

  // Layer 2: h2 = relu(h1 @ W2 + b2).
  {
    const float bias = b2[t];
    float acc0 = bias, acc1 = bias;
#pragma unroll 4
    for (int k = 0; k < H; ++k) {
      const float w = W2[k * H + t];
      acc0 += s_h1[0][k] * w;
      acc1 += s_h1[1][k] * w;
    }
    s_h2[0][t] = fmaxf(acc0, 0.f);
    s_h2[1][t] = fmaxf(acc1, 0.f);
  }
  __syncthreads();

  // Layer 3: out = h2 @ W3 + b3. BB*C = 10 outputs; one wave per output.
  const int wv = t >> 6;
  const int ln = t & 63;
  for (int oi = wv; oi < BB * C; oi += 8) {
    const int bb = oi / C;
    const int c = oi - bb * C;
    float a = 0.f;
#pragma unroll
    for (int h = ln; h < H; h += 64) a += s_h2[bb][h] * W3[h * C + c];
#pragma unroll
    for (int off = 32; off > 0; off >>= 1) a += __shfl_down(a, off);
    if (ln == 0) out[(r0 + bb) * C + c] = a + b3[c];
  }
}

// ---------------------------------------------------------------------------
extern "C" void kernel_launch(void* const* d_in, const int* in_sizes, int n_in,
                              void* d_out, int out_size, void* d_ws,
                              size_t ws_size, hipStream_t stream) {
  const float* emb  = (const float*)d_in[0];
  const float* W1   = (const float*)d_in[1];
  const float* b1   = (const float*)d_in[2];
  const float* W2   = (const float*)d_in[3];
  const float* b2   = (const float*)d_in[4];
  const float* W3   = (const float*)d_in[5];
  const float* b3   = (const float*)d_in[6];
  const int*   docs = (const int*)d_in[7];
  const int*   dlen = (const int*)d_in[8];
  float* out = (float*)d_out;
  float* partial = (float*)d_ws;  // B*SPLIT*D floats = 3.07 MB

  dim3 g1(B, SPLIT);
  gather_sum_kernel<<<g1, 320, 0, stream>>>(emb, docs, partial);
  mlp_kernel<<<B / BB, 512, 0, stream>>>(partial, dlen, W1, b1, W2, b2, W3,
                                         b3, out);
}

// Round 2
// 76.369 us; speedup vs baseline: 1.4961x; 1.4961x over previous
//
#include <hip/hip_runtime.h>

#define VOCAB 100000
#define D     300
#define B     256
#define L     1000
#define H     512
#define C     5

#define SPLIT 10
#define CHUNK (L / SPLIT)   // 100 rows per gather block
#define D4    (D / 4)       // 75 float4 per row
#define KH1   (D / 2)       // 150: layer-1 K half
#define KH2   (H / 2)       // 256: layer-2 K half

// ws layout (floats)
#define WS_PARTIAL 0
#define WS_H1      (B * SPLIT * D)            // 768000
#define WS_H2      (WS_H1 + B * H)            // 899072; total 1030144 f = 4.12 MB

// ---------------------------------------------------------------------------
// Kernel 1: gather + partial sum (unchanged — ~15 us, L3-served).
// grid = (B, SPLIT), block = 320 = 4 row-groups x 80 lanes, float4 loads.
// ---------------------------------------------------------------------------
__global__ __launch_bounds__(320) void gather_sum_kernel(
    const float* __restrict__ emb, const int* __restrict__ docs,
    float* __restrict__ partial) {
  const int b = blockIdx.x;
  const int s = blockIdx.y;
  const int t = threadIdx.x;
  const int rg = t / 80;
  const int lane = t - rg * 80;

  __shared__ int sidx[CHUNK];
  if (t < CHUNK) sidx[t] = docs[b * L + s * CHUNK + t];
  __syncthreads();

  float ax = 0.f, ay = 0.f, az = 0.f, aw = 0.f;
  if (lane < D4) {
#pragma unroll 5
    for (int l = 0; l < CHUNK; l += 4) {
      const int idx = sidx[l + rg];
      const float4 v =
          reinterpret_cast<const float4*>(emb + (size_t)idx * D)[lane];
      ax += v.x; ay += v.y; az += v.z; aw += v.w;
    }
  }

  __shared__ float4 sred[3][D4];
  if (rg > 0 && lane < D4) sred[rg - 1][lane] = make_float4(ax, ay, az, aw);
  __syncthreads();
  if (rg == 0 && lane < D4) {
#pragma unroll
    for (int g = 0; g < 3; ++g) {
      const float4 v = sred[g][lane];
      ax += v.x; ay += v.y; az += v.z; aw += v.w;
    }
    reinterpret_cast<float4*>(partial + (size_t)(b * SPLIT + s) * D)[lane] =
        make_float4(ax, ay, az, aw);
  }
}

// ---------------------------------------------------------------------------
// Layer 1: h1 = relu(avg @ W1 + b1).
// grid = (B/2, 2 hidden-halves) = 256 blocks; block = 512 = 256 cols x 2 k-halves.
// Each block: 2 batch rows. Weight loads coalesced (lane = consecutive col).
// ---------------------------------------------------------------------------
__global__ __launch_bounds__(512) void l1_kernel(
    const float* __restrict__ partial, const int* __restrict__ dlen,
    const float* __restrict__ W1, const float* __restrict__ b1,
    float* __restrict__ h1) {
  const int bt = blockIdx.x;
  const int ht = blockIdx.y;
  const int t = threadIdx.x;
  const int cl = t & 255;
  const int kh = t >> 8;
  const int col = ht * 256 + cl;

  __shared__ float s_avg[2][D];
  for (int i = t; i < 2 * D; i += 512) {
    const int r = i < D ? 0 : 1;
    const int d = i - r * D;
    const int b = bt * 2 + r;
    const float* p = partial + (size_t)b * (SPLIT * D) + d;
    float s = 0.f;
#pragma unroll
    for (int k = 0; k < SPLIT; ++k) s += p[k * D];
    s_avg[r][d] = s / (float)dlen[b];
  }
  __syncthreads();

  float a0 = 0.f, a1 = 0.f;
  const int k0 = kh * KH1;
#pragma unroll 15
  for (int k = k0; k < k0 + KH1; ++k) {
    const float w = W1[k * H + col];
    a0 += s_avg[0][k] * w;
    a1 += s_avg[1][k] * w;
  }

  __shared__ float s_part[2][256];
  if (kh == 1) { s_part[0][cl] = a0; s_part[1][cl] = a1; }
  __syncthreads();
  if (kh == 0) {
    const float bias = b1[col];
    h1[(size_t)(bt * 2 + 0) * H + col] = fmaxf(a0 + s_part[0][cl] + bias, 0.f);
    h1[(size_t)(bt * 2 + 1) * H + col] = fmaxf(a1 + s_part[1][cl] + bias, 0.f);
  }
}

// ---------------------------------------------------------------------------
// Layer 2: h2 = relu(h1 @ W2 + b2). Same structure, K = 512.
// ---------------------------------------------------------------------------
__global__ __launch_bounds__(512) void l2_kernel(
    const float* __restrict__ h1, const float* __restrict__ W2,
    const float* __restrict__ b2, float* __restrict__ h2) {
  const int bt = blockIdx.x;
  const int ht = blockIdx.y;
  const int t = threadIdx.x;
  const int cl = t & 255;
  const int kh = t >> 8;
  const int col = ht * 256 + cl;

  __shared__ float s_h[2][H];
  for (int i = t; i < 2 * H; i += 512)
    s_h[i >> 9][i & (H - 1)] = h1[(size_t)bt * 2 * H + i];
  __syncthreads();

  float a0 = 0.f, a1 = 0.f;
  const int k0 = kh * KH2;
#pragma unroll 16
  for (int k = k0; k < k0 + KH2; ++k) {
    const float w = W2[k * H + col];
    a0 += s_h[0][k] * w;
    a1 += s_h[1][k] * w;
  }

  __shared__ float s_part[2][256];
  if (kh == 1) { s_part[0][cl] = a0; s_part[1][cl] = a1; }
  __syncthreads();
  if (kh == 0) {
    const float bias = b2[col];
    h2[(size_t)(bt * 2 + 0) * H + col] = fmaxf(a0 + s_part[0][cl] + bias, 0.f);
    h2[(size_t)(bt * 2 + 1) * H + col] = fmaxf(a1 + s_part[1][cl] + bias, 0.f);
  }
}

// ---------------------------------------------------------------------------
// Head: out = h2 @ W3 + b3. 256 blocks x 64 threads (one wave per row).
// W3 is 10 KB -> L1-resident despite strided access.
// ---------------------------------------------------------------------------
__global__ __launch_bounds__(64) void head_kernel(
    const float* __restrict__ h2, const float* __restrict__ W3,
    const float* __restrict__ b3, float* __restrict__ out) {
  const int b = blockIdx.x;
  const int l = threadIdx.x;
  float acc[C] = {0.f, 0.f, 0.f, 0.f, 0.f};
#pragma unroll
  for (int i = 0; i < H / 64; ++i) {
    const int h = i * 64 + l;
    const float v = h2[(size_t)b * H + h];
#pragma unroll
    for (int c = 0; c < C; ++c) acc[c] += v * W3[h * C + c];
  }
#pragma unroll
  for (int c = 0; c < C; ++c) {
    float a = acc[c];
#pragma unroll
    for (int off = 32; off > 0; off >>= 1) a += __shfl_down(a, off);
    if (l == 0) out[b * C + c] = a + b3[c];
  }
}

// ---------------------------------------------------------------------------
extern "C" void kernel_launch(void* const* d_in, const int* in_sizes, int n_in,
                              void* d_out, int out_size, void* d_ws,
                              size_t ws_size, hipStream_t stream) {
  const float* emb  = (const float*)d_in[0];
  const float* W1   = (const float*)d_in[1];
  const float* b1   = (const float*)d_in[2];
  const float* W2   = (const float*)d_in[3];
  const float* b2   = (const float*)d_in[4];
  const float* W3   = (const float*)d_in[5];
  const float* b3   = (const float*)d_in[6];
  const int*   docs = (const int*)d_in[7];
  const int*   dlen = (const int*)d_in[8];
  float* out = (float*)d_out;

  float* ws = (float*)d_ws;
  float* partial = ws + WS_PARTIAL;
  float* h1 = ws + WS_H1;
  float* h2 = ws + WS_H2;

  dim3 g1(B, SPLIT);
  gather_sum_kernel<<<g1, 320, 0, stream>>>(emb, docs, partial);
  dim3 g2(B / 2, 2);
  l1_kernel<<<g2, 512, 0, stream>>>(partial, dlen, W1, b1, h1);
  l2_kernel<<<g2, 512, 0, stream>>>(h1, W2, b2, h2);
  head_kernel<<<B, 64, 0, stream>>>(h2, W3, b3, out);
}